// Round 3
// baseline (441.249 us; speedup 1.0000x reference)
//
#include <hip/hip_runtime.h>

// DigitCaps matvec: u_hat[b,r,c,o] = sum_i W[r,c,o,i]*x[b,r,i] + bias[o]
// B=512 R=1152 C=10 O=16 I=8. All tensors FLOAT32.
//
// R4 decomposition theory: dur_us (428.7) = harness poison fill (242 us,
// 1.51 GB @ 6.24 TB/s, top-5 proves it) + ~10 reset dispatches/gaps (~120 us)
// + our kernel (~67 us ~= 95% of the 63.8 us traffic floor: 377.5 MB write
// + 25 MB read @ 6.3 TB/s). The R2 store-layout fix won 12 us because the
// kernel was already near-BW-bound, not 199 us as assumed in R1.
//
// This round = discriminating probe + last micro-opts:
//  - explicit x double-buffer prefetch (next batch's x issued before FMAs)
//  - nontemporal x loads (x is read exactly ONCE globally -> L2 bypass free;
//    W loads stay CACHED: W is reused by 32 blockIdx.y groups via L2/L3)
// Pre-committed reading: delta within +-6 us => kernel is at roofline;
// delta < -20 us => latency-bound hypothesis was right, iterate pipelining.

#define B_ 512
#define R_ 1152
#define C_ 10
#define O_ 16
#define I_ 8
#define CO_ 160               // C*O, contiguous inner extent per (b,r)
#define SLOTS 40              // 160 outputs / 4 per thread
#define RPB 8                 // consecutive r rows per block
#define NTHREADS (RPB * SLOTS)   // 320 = 5 waves, zero idle lanes
#define NB 16                 // batches per block (W-frag reuse factor)

typedef float f32x4 __attribute__((ext_vector_type(4)));

__global__ __launch_bounds__(NTHREADS) void digitcaps_kernel(
    const float* __restrict__ x,     // [B,R,I]
    const float* __restrict__ W,     // [R,C,O,I]
    const float* __restrict__ bias,  // [O]
    float* __restrict__ out)         // [B,R,C,O]
{
    const int t  = threadIdx.x;
    const int rr = t / SLOTS;         // r within chunk, 0..7
    const int s  = t - rr * SLOTS;    // slot 0..39: c = s>>2, o-quad = s&3
    const int r  = blockIdx.x * RPB + rr;

    // W fragment for this (r, c, o-quad): 4 rows x 8 i = 32 f32 = 128B contiguous.
    // CACHED loads on purpose (reused across 32 b-groups through L2/L3).
    const f32x4* wp = (const f32x4*)(W + ((size_t)r * CO_ + (size_t)s * 4) * I_);
    float w[4][8];
#pragma unroll
    for (int j = 0; j < 4; ++j) {
        f32x4 lo = wp[2 * j];
        f32x4 hi = wp[2 * j + 1];
        w[j][0] = lo.x; w[j][1] = lo.y; w[j][2] = lo.z; w[j][3] = lo.w;
        w[j][4] = hi.x; w[j][5] = hi.y; w[j][6] = hi.z; w[j][7] = hi.w;
    }

    // bias for this o-quad: 4 f32 = 16B
    f32x4 bv = ((const f32x4*)bias)[s & 3];
    float bsf[4] = {bv.x, bv.y, bv.z, bv.w};

    const int b0 = blockIdx.y * NB;
    const float* xp = x + ((size_t)b0 * R_ + r) * I_;
    // Block's stores per iteration: base + t*16 bytes, t=0..319 -> 5120B contiguous.
    float*       op = out + ((size_t)b0 * R_ + r) * CO_ + (size_t)s * 4;

    // x double-buffer: prefetch batch b0's x before the loop; inside the loop
    // issue batch b+1's loads before the FMAs so HBM latency hides under compute.
    // x is read exactly once globally -> nontemporal (no L2 pollution of W).
    f32x4 xlo = __builtin_nontemporal_load((const f32x4*)xp);
    f32x4 xhi = __builtin_nontemporal_load((const f32x4*)xp + 1);

#pragma unroll
    for (int bb = 0; bb < NB; ++bb) {
        // capture current x into scalars before overwriting the prefetch regs
        float xf[8] = {xlo.x, xlo.y, xlo.z, xlo.w, xhi.x, xhi.y, xhi.z, xhi.w};

        if (bb + 1 < NB) {
            xp += (size_t)R_ * I_;
            xlo = __builtin_nontemporal_load((const f32x4*)xp);
            xhi = __builtin_nontemporal_load((const f32x4*)xp + 1);
        }

        float acc[4];
#pragma unroll
        for (int j = 0; j < 4; ++j) acc[j] = bsf[j];
#pragma unroll
        for (int i = 0; i < 8; ++i)
#pragma unroll
            for (int j = 0; j < 4; ++j)
                acc[j] = fmaf(xf[i], w[j][i], acc[j]);

        // 4 contiguous f32 outputs; block iteration = 5120B contiguous stream.
        // Nontemporal: write-once data, don't thrash W out of L2.
        f32x4 ov = {acc[0], acc[1], acc[2], acc[3]};
        __builtin_nontemporal_store(ov, (f32x4*)op);

        op += (size_t)R_ * CO_;
    }
}

extern "C" void kernel_launch(void* const* d_in, const int* in_sizes, int n_in,
                              void* d_out, int out_size, void* d_ws, size_t ws_size,
                              hipStream_t stream) {
    const float* x    = (const float*)d_in[0];
    const float* W    = (const float*)d_in[1];
    const float* bias = (const float*)d_in[2];
    float* out        = (float*)d_out;

    dim3 grid(R_ / RPB, B_ / NB);  // (144, 32)
    digitcaps_kernel<<<grid, NTHREADS, 0, stream>>>(x, W, bias, out);
}

// Round 4
// 428.734 us; speedup vs baseline: 1.0292x; 1.0292x over previous
//
#include <hip/hip_runtime.h>

// DigitCaps matvec: u_hat[b,r,c,o] = sum_i W[r,c,o,i]*x[b,r,i] + bias[o]
// B=512 R=1152 C=10 O=16 I=8. All tensors FLOAT32.
//
// FINAL (R4 = revert to R2, the best measured config: 428.7 us):
// Decomposition (confirmed by R3's discriminating probe): dur_us =
// harness poison fill (242 us, 1.51 GB @ 6.2 TB/s, tops every profile)
// + ~10 reset dispatches/gaps (~120 us) + this kernel (~67 us vs the
// 63.8 us traffic floor: 377.5 MB mandatory write + 25 MB read @ 6.3 TB/s).
// R3's x-prefetch + nontemporal-x-loads probe showed NO latency win
// (+12.6 us, reverted) -> kernel is BW-bound within ~5% of roofline.
//
// Structure: 8 consecutive r rows per block x 40 slots -> each block
// iteration stores 5120 CONTIGUOUS bytes (1024B per wave); consecutive
// blocks cover adjacent r-chunks. W fragment (32 f32) register-resident,
// reused over NB=16 batches; nt stores keep W L2-resident against the
// 377 MB write stream. x/W loads stay CACHED (R3 proved nt-x hurts/neutral).

#define B_ 512
#define R_ 1152
#define C_ 10
#define O_ 16
#define I_ 8
#define CO_ 160               // C*O, contiguous inner extent per (b,r)
#define SLOTS 40              // 160 outputs / 4 per thread
#define RPB 8                 // consecutive r rows per block
#define NTHREADS (RPB * SLOTS)   // 320 = 5 waves, zero idle lanes
#define NB 16                 // batches per block (W-frag reuse factor)

typedef float f32x4 __attribute__((ext_vector_type(4)));

__global__ __launch_bounds__(NTHREADS) void digitcaps_kernel(
    const float* __restrict__ x,     // [B,R,I]
    const float* __restrict__ W,     // [R,C,O,I]
    const float* __restrict__ bias,  // [O]
    float* __restrict__ out)         // [B,R,C,O]
{
    const int t  = threadIdx.x;
    const int rr = t / SLOTS;         // r within chunk, 0..7
    const int s  = t - rr * SLOTS;    // slot 0..39: c = s>>2, o-quad = s&3
    const int r  = blockIdx.x * RPB + rr;

    // W fragment for this (r, c, o-quad): 4 rows x 8 i = 32 f32 = 128B contiguous.
    // Flat element offset: ((r*C + c)*O + (s&3)*4)*I = (r*CO_ + s*4)*I
    const f32x4* wp = (const f32x4*)(W + ((size_t)r * CO_ + (size_t)s * 4) * I_);
    float w[4][8];
#pragma unroll
    for (int j = 0; j < 4; ++j) {
        f32x4 lo = wp[2 * j];
        f32x4 hi = wp[2 * j + 1];
        w[j][0] = lo.x; w[j][1] = lo.y; w[j][2] = lo.z; w[j][3] = lo.w;
        w[j][4] = hi.x; w[j][5] = hi.y; w[j][6] = hi.z; w[j][7] = hi.w;
    }

    // bias for this o-quad: 4 f32 = 16B
    f32x4 bv = ((const f32x4*)bias)[s & 3];
    float bsf[4] = {bv.x, bv.y, bv.z, bv.w};

    const int b0 = blockIdx.y * NB;
    const float* xp = x + ((size_t)b0 * R_ + r) * I_;
    // Block's stores per iteration: base + t*16 bytes, t=0..319 -> 5120B contiguous.
    float*       op = out + ((size_t)b0 * R_ + r) * CO_ + (size_t)s * 4;

#pragma unroll 4
    for (int bb = 0; bb < NB; ++bb) {
        // x[b,r,0:8] — two 16B loads, uniform across the 40-lane group (cache broadcast)
        f32x4 xlo = ((const f32x4*)xp)[0];
        f32x4 xhi = ((const f32x4*)xp)[1];
        float xf[8] = {xlo.x, xlo.y, xlo.z, xlo.w, xhi.x, xhi.y, xhi.z, xhi.w};

        float acc[4];
#pragma unroll
        for (int j = 0; j < 4; ++j) acc[j] = bsf[j];
#pragma unroll
        for (int i = 0; i < 8; ++i)
#pragma unroll
            for (int j = 0; j < 4; ++j)
                acc[j] = fmaf(xf[i], w[j][i], acc[j]);

        // 4 contiguous f32 outputs; block iteration = 5120B contiguous stream.
        // Nontemporal: write-once data, don't thrash W out of L2.
        f32x4 ov = {acc[0], acc[1], acc[2], acc[3]};
        __builtin_nontemporal_store(ov, (f32x4*)op);

        xp += (size_t)R_ * I_;
        op += (size_t)R_ * CO_;
    }
}

extern "C" void kernel_launch(void* const* d_in, const int* in_sizes, int n_in,
                              void* d_out, int out_size, void* d_ws, size_t ws_size,
                              hipStream_t stream) {
    const float* x    = (const float*)d_in[0];
    const float* W    = (const float*)d_in[1];
    const float* bias = (const float*)d_in[2];
    float* out        = (float*)d_out;

    dim3 grid(R_ / RPB, B_ / NB);  // (144, 32)
    digitcaps_kernel<<<grid, NTHREADS, 0, stream>>>(x, W, bias, out);
}